// Round 1
// baseline (781.106 us; speedup 1.0000x reference)
//
#include <hip/hip_runtime.h>

#define S 2048
#define D 64
#define BH 32
#define BR 64
#define BC 64
#define PITCH 72  // bf16 elements per LDS row (144B: conflict-free b128 frag reads)

typedef __attribute__((ext_vector_type(8))) short bf16x8;
typedef __attribute__((ext_vector_type(4))) float f32x4;

__device__ __forceinline__ unsigned short f2bf(float f) {
    union { float f; unsigned u; } v; v.f = f;
    unsigned u = v.u;
    return (unsigned short)((u + 0x7FFFu + ((u >> 16) & 1u)) >> 16);  // RNE
}

// Stage a 64x64 fp32 row-major tile (row stride D) -> bf16 LDS tile [64][PITCH]
__device__ __forceinline__ void stage_tile(const float* __restrict__ src,
                                           unsigned short* lds, int t) {
#pragma unroll
    for (int i = 0; i < 4; ++i) {
        int idx = i * 256 + t;      // 0..1023
        int r = idx >> 4;           // row 0..63
        int c4 = idx & 15;          // float4 group 0..15
        const float4 f = *(const float4*)(src + r * D + c4 * 4);
        ushort4 h;
        h.x = f2bf(f.x); h.y = f2bf(f.y); h.z = f2bf(f.z); h.w = f2bf(f.w);
        *(ushort4*)(lds + r * PITCH + c4 * 4) = h;   // 8B aligned (144B pitch)
    }
}

// Stage V 64(key)x64(d) fp32 tile transposed -> Vt[d][key] bf16 LDS [64][PITCH]
__device__ __forceinline__ void stage_vT(const float* __restrict__ src,
                                         unsigned short* lds, int t) {
#pragma unroll
    for (int i = 0; i < 4; ++i) {
        int idx = i * 256 + t;
        int r = idx >> 4;           // key row 0..63
        int c4 = idx & 15;          // d group
        const float4 f = *(const float4*)(src + r * D + c4 * 4);
        lds[(c4 * 4 + 0) * PITCH + r] = f2bf(f.x);
        lds[(c4 * 4 + 1) * PITCH + r] = f2bf(f.y);
        lds[(c4 * 4 + 2) * PITCH + r] = f2bf(f.z);
        lds[(c4 * 4 + 3) * PITCH + r] = f2bf(f.w);
    }
}

// Kernel 1: per-row softmax stats (m = rowmax of s, l = sum exp(s-m)).
// Stats stored in weights buffer at W[row][0] (m) and W[row][1] (l);
// each attn_main block reads only its own rows' stats before overwriting.
__global__ __launch_bounds__(256, 4) void attn_stats(const float* __restrict__ q,
                                                     const float* __restrict__ k,
                                                     float* __restrict__ w) {
    __shared__ unsigned short Qt[BR * PITCH];
    __shared__ unsigned short Kt[BC * PITCH];
    const int bh = blockIdx.y;
    const int q0 = blockIdx.x * BR;
    const int t = threadIdx.x;
    const int lane = t & 63, wave = t >> 6;
    const int quad = lane >> 4, n = lane & 15;

    stage_tile(q + ((size_t)bh * S + q0) * D, Qt, t);
    __syncthreads();

    bf16x8 aq[2];
    aq[0] = *(const bf16x8*)(Qt + (wave * 16 + n) * PITCH + 0 * 32 + quad * 8);
    aq[1] = *(const bf16x8*)(Qt + (wave * 16 + n) * PITCH + 1 * 32 + quad * 8);

    float m_r[4] = {-INFINITY, -INFINITY, -INFINITY, -INFINITY};
    float l_r[4] = {0.f, 0.f, 0.f, 0.f};

    for (int kc = 0; kc < S / BC; ++kc) {
        __syncthreads();
        stage_tile(k + ((size_t)bh * S + kc * BC) * D, Kt, t);
        __syncthreads();

        f32x4 acc[4];
#pragma unroll
        for (int nt = 0; nt < 4; ++nt) {
            f32x4 a = {0.f, 0.f, 0.f, 0.f};
#pragma unroll
            for (int c = 0; c < 2; ++c) {
                bf16x8 bk = *(const bf16x8*)(Kt + (nt * 16 + n) * PITCH + c * 32 + quad * 8);
                a = __builtin_amdgcn_mfma_f32_16x16x32_bf16(aq[c], bk, a, 0, 0, 0);
            }
            acc[nt] = a;
        }
        float sc[4][4];
#pragma unroll
        for (int nt = 0; nt < 4; ++nt)
#pragma unroll
            for (int r = 0; r < 4; ++r) sc[nt][r] = acc[nt][r] * 0.125f;

        float tm[4];
#pragma unroll
        for (int r = 0; r < 4; ++r)
            tm[r] = fmaxf(fmaxf(sc[0][r], sc[1][r]), fmaxf(sc[2][r], sc[3][r]));
#pragma unroll
        for (int msk = 1; msk <= 8; msk <<= 1)
#pragma unroll
            for (int r = 0; r < 4; ++r) tm[r] = fmaxf(tm[r], __shfl_xor(tm[r], msk, 64));

        float ps[4];
#pragma unroll
        for (int r = 0; r < 4; ++r) {
            float nm = fmaxf(m_r[r], tm[r]);
            float alpha = __expf(m_r[r] - nm);
            ps[r] = __expf(sc[0][r] - nm) + __expf(sc[1][r] - nm)
                  + __expf(sc[2][r] - nm) + __expf(sc[3][r] - nm);
            m_r[r] = nm;
            l_r[r] *= alpha;
        }
#pragma unroll
        for (int msk = 1; msk <= 8; msk <<= 1)
#pragma unroll
            for (int r = 0; r < 4; ++r) ps[r] += __shfl_xor(ps[r], msk, 64);
#pragma unroll
        for (int r = 0; r < 4; ++r) l_r[r] += ps[r];
    }

    if (n == 0) {
#pragma unroll
        for (int r = 0; r < 4; ++r) {
            size_t row = (size_t)bh * S + (q0 + wave * 16 + quad * 4 + r);
            w[row * S + 0] = m_r[r];
            w[row * S + 1] = l_r[r];
        }
    }
}

// Kernel 2: recompute S, write normalized weights, accumulate O = P.V
__global__ __launch_bounds__(256, 4) void attn_main(const float* __restrict__ q,
                                                    const float* __restrict__ k,
                                                    const float* __restrict__ v,
                                                    float* __restrict__ o,
                                                    float* __restrict__ w) {
    __shared__ unsigned short Qt[BR * PITCH];
    __shared__ unsigned short Kt[BC * PITCH];
    __shared__ unsigned short Vt[D * PITCH];   // transposed: Vt[d][key]
    __shared__ unsigned short Pt[BR * PITCH];
    const int bh = blockIdx.y;
    const int q0 = blockIdx.x * BR;
    const int t = threadIdx.x;
    const int lane = t & 63, wave = t >> 6;
    const int quad = lane >> 4, n = lane & 15;

    stage_tile(q + ((size_t)bh * S + q0) * D, Qt, t);
    __syncthreads();
    bf16x8 aq[2];
    aq[0] = *(const bf16x8*)(Qt + (wave * 16 + n) * PITCH + 0 * 32 + quad * 8);
    aq[1] = *(const bf16x8*)(Qt + (wave * 16 + n) * PITCH + 1 * 32 + quad * 8);

    // per-row stats (must load before any weight writes of kc==0)
    float mr[4], rl[4];
#pragma unroll
    for (int r = 0; r < 4; ++r) {
        size_t row = (size_t)bh * S + (q0 + wave * 16 + quad * 4 + r);
        mr[r] = w[row * S + 0];
        rl[r] = 1.0f / w[row * S + 1];
    }

    f32x4 accO[4] = {{0.f,0.f,0.f,0.f},{0.f,0.f,0.f,0.f},{0.f,0.f,0.f,0.f},{0.f,0.f,0.f,0.f}};

    for (int kc = 0; kc < S / BC; ++kc) {
        __syncthreads();
        stage_tile(k + ((size_t)bh * S + kc * BC) * D, Kt, t);
        stage_vT(v + ((size_t)bh * S + kc * BC) * D, Vt, t);
        __syncthreads();

#pragma unroll
        for (int nt = 0; nt < 4; ++nt) {
            f32x4 a = {0.f, 0.f, 0.f, 0.f};
#pragma unroll
            for (int c = 0; c < 2; ++c) {
                bf16x8 bk = *(const bf16x8*)(Kt + (nt * 16 + n) * PITCH + c * 32 + quad * 8);
                a = __builtin_amdgcn_mfma_f32_16x16x32_bf16(aq[c], bk, a, 0, 0, 0);
            }
            float pr[4];
#pragma unroll
            for (int r = 0; r < 4; ++r)
                pr[r] = __expf(a[r] * 0.125f - mr[r]) * rl[r];

            // global weights store: 16 lanes x 4B = 64B contiguous per quad-row
            float* wrow = w + ((size_t)(bh * S + q0 + wave * 16 + quad * 4)) * S
                            + (size_t)kc * BC + nt * 16 + n;
#pragma unroll
            for (int r = 0; r < 4; ++r) wrow[(size_t)r * S] = pr[r];

            // P (bf16) into LDS for A-frag reload (wave-private rows -> no barrier)
#pragma unroll
            for (int r = 0; r < 4; ++r)
                Pt[(wave * 16 + quad * 4 + r) * PITCH + nt * 16 + n] = f2bf(pr[r]);
        }

        // PV: A = P[qrow][key], B = Vt[d][key] (B-frag: lane n -> d, elems -> key)
#pragma unroll
        for (int c = 0; c < 2; ++c) {
            bf16x8 ap = *(const bf16x8*)(Pt + (wave * 16 + n) * PITCH + c * 32 + quad * 8);
#pragma unroll
            for (int nt = 0; nt < 4; ++nt) {
                bf16x8 bv = *(const bf16x8*)(Vt + (nt * 16 + n) * PITCH + c * 32 + quad * 8);
                accO[nt] = __builtin_amdgcn_mfma_f32_16x16x32_bf16(ap, bv, accO[nt], 0, 0, 0);
            }
        }
    }

#pragma unroll
    for (int nt = 0; nt < 4; ++nt)
#pragma unroll
        for (int r = 0; r < 4; ++r)
            o[((size_t)bh * S + q0 + wave * 16 + quad * 4 + r) * D + nt * 16 + n] = accO[nt][r];
}

extern "C" void kernel_launch(void* const* d_in, const int* in_sizes, int n_in,
                              void* d_out, int out_size, void* d_ws, size_t ws_size,
                              hipStream_t stream) {
    const float* q = (const float*)d_in[0];
    const float* k = (const float*)d_in[1];
    const float* v = (const float*)d_in[2];
    float* o = (float*)d_out;
    float* w = o + (size_t)BH * S * D;   // weights region follows O

    dim3 grid(S / BR, BH);
    attn_stats<<<grid, dim3(256), 0, stream>>>(q, k, w);
    attn_main<<<grid, dim3(256), 0, stream>>>(q, k, v, o, w);
}